// Round 2
// baseline (332.335 us; speedup 1.0000x reference)
//
#include <hip/hip_runtime.h>
#include <hip/hip_bf16.h>
#include <hip/hip_cooperative_groups.h>

namespace cg = cooperative_groups;

// Problem constants
#define N_PAIRS   64000
#define N_ATOMS   16000
#define N_FEAT    8
#define N_HIDDEN  100
// Aggregate-first, fused, scalar-metadata pipeline, now ONE cooperative kernel:
//   phase 0: zero deg (atomicExch -> coherent point) + build wtb2[i][k]=Wbig[k][i]
//   grid.sync()
//   phase 1: histogram edges by dest, bucket packs (e<<14)|src
//   grid.sync()
//   phase 2: per dest-tile (16 atoms): wave-uniform edge loop, SGPR metadata,
//            af float2 gather by lanes 0..49, S-tile in LDS (bf16),
//            out = S_tile @ wtb2^T via 16x16x32 bf16 MFMA.
// Rationale: both previous kernels were individually <41us (below the harness
// poison fills in top-5) yet total was ~103us across 4 dispatches; this merge
// removes the memset dispatch + 2 launch boundaries, and makes the single
// kernel big enough to surface in rocprof top-5 with real counters.
#define SW        1024    // wtb2 row stride (stored transposed: wtb2[i][k])
#define SKL       936     // LDS S-tile row stride (bf16)
#define MAX_DEG   32      // bucket stride per dest (P(deg>32|Poisson(4))~1e-18)

#define GRID_B    500
#define TPB       512
#define TILES_PER_BLOCK 2          // 500 * 2 = 1000 tiles = 16000 dests

#define SETUP_BLOCKS (112 * 1024 / 256)    // 448  (fallback path)
#define HIST_BLOCKS  (N_PAIRS / 256)       // 250  (fallback path)

typedef __attribute__((ext_vector_type(8))) short bf16x8_t;   // 8 bf16 = 4 VGPRs
typedef __attribute__((ext_vector_type(4))) float f32x4_t;

__global__ __launch_bounds__(TPB, 4) void mega(const float* __restrict__ pf,
                                               const float* __restrict__ af,
                                               const int* __restrict__ a2p,
                                               const float* __restrict__ W,
                                               const float* __restrict__ bias,
                                               __hip_bfloat16* __restrict__ wtb2,
                                               int* __restrict__ deg,
                                               unsigned* __restrict__ bucket,
                                               float* __restrict__ out) {
    cg::grid_group gg = cg::this_grid();
    __shared__ __hip_bfloat16 St[16 * SKL];            // 29,952 B -> 2 blocks/CU
    const int tid  = threadIdx.x;
    const int gtid = blockIdx.x * TPB + tid;           // < 256000

    // ---- phase 0: zero deg (atomic -> lands at coherent point) + build wtb2
    if (gtid < N_ATOMS) atomicExch(&deg[gtid], 0);
    if (gtid < 112 * 1024) {
        int i = gtid >> 10;                    // 0..111 (output col)
        int k = gtid & 1023;                   // 0..1023 (contraction index)
        float v = 0.f;
        if (i < N_HIDDEN) {
            if (k < 800) {
                int f = k / N_HIDDEN;
                int j = k - f * N_HIDDEN;
                v = W[f * (N_HIDDEN * N_HIDDEN) + i * N_HIDDEN + j];
            } else if (k < 900) {
                v = bias[i * N_HIDDEN + (k - 800)];
            }
        }
        wtb2[gtid] = __float2bfloat16(v);
    }
    __threadfence();                                   // flush wtb2 out of this XCD's L2
    gg.sync();

    // ---- phase 1: histogram (bucket edges by dest)
    if (gtid < N_PAIRS) {
        int dest = a2p[gtid * 2];
        int src  = a2p[gtid * 2 + 1];
        int slot = atomicAdd(&deg[dest], 1);
        if (slot < MAX_DEG)
            bucket[dest * MAX_DEG + slot] = ((unsigned)gtid << 14) | (unsigned)src;
    }
    __threadfence();                                   // flush bucket stores
    gg.sync();

    // ---- phase 2: fused aggregation + GEMM, 2 tiles per block
    const int wave = tid >> 6;
    const int lane = tid & 63;
    const bool act = (lane < 50);                      // cols 2*lane, 2*lane+1

    for (int it = 0; it < TILES_PER_BLOCK; ++it) {
        const int tile = blockIdx.x + GRID_B * it;     // 0..999

#pragma unroll
        for (int j = 0; j < 2; ++j) {
            int r = wave * 2 + j;                      // tile row 0..15
            int d = __builtin_amdgcn_readfirstlane(tile * 16 + r);   // force SGPR
            int n = deg[d];                            // scalar load
            if (n > MAX_DEG) n = MAX_DEG;

            const unsigned* sb = bucket + (size_t)d * MAX_DEG;       // SGPR base

            float acc[9][2] = {};                      // f=0..7 weighted, f=8 bias
            for (int t0 = 0; t0 < n; t0 += 4) {
                float2 a[4];
                unsigned pk[4];
#pragma unroll
                for (int u = 0; u < 4; ++u) {
                    int t = t0 + u;
                    pk[u] = sb[t < n ? t : 0];         // scalar load (clamped)
                    int src = (int)(pk[u] & 16383u);   // SGPR
                    if (t < n && act)
                        a[u] = *(const float2*)(af + src * N_HIDDEN + 2 * lane);
                    else
                        a[u] = make_float2(0.f, 0.f);
                }
#pragma unroll
                for (int u = 0; u < 4; ++u) {
                    int e = (int)(pk[u] >> 14);        // SGPR edge id
                    const float* pe = pf + e * N_FEAT; // dense, L2-hot
#pragma unroll
                    for (int f = 0; f < N_FEAT; ++f) {
                        float p = pe[f];               // scalar load -> SGPR operand
                        acc[f][0] += p * a[u].x;
                        acc[f][1] += p * a[u].y;
                    }
                    acc[8][0] += a[u].x;
                    acc[8][1] += a[u].y;
                }
            }

            // write S row to LDS (bf16); lanes 50..63 zero K-pad cols 900..927
            __hip_bfloat16* srow = St + r * SKL;
            if (act) {
#pragma unroll
                for (int f = 0; f < 9; ++f) {
                    __hip_bfloat162 h;
                    h.x = __float2bfloat16(acc[f][0]);
                    h.y = __float2bfloat16(acc[f][1]);
                    *(__hip_bfloat162*)(srow + f * N_HIDDEN + 2 * lane) = h;
                }
            } else {
                __hip_bfloat162 z;
                z.x = __float2bfloat16(0.f);
                z.y = z.x;
                *(__hip_bfloat162*)(srow + 900 + 2 * (lane - 50)) = z;   // 900..927
            }
        }
        __syncthreads();

        // out[16 rows] = S_tile @ wtb2^T; wave w -> n-tile w (w<7)
        if (wave < 7) {
            int quad = lane >> 4;
            int l15  = lane & 15;
            int m0   = tile * 16;
            const __hip_bfloat16* as = St + l15 * SKL + quad * 8;
            const __hip_bfloat16* bp = wtb2 + (size_t)(wave * 16 + l15) * SW + quad * 8;
            f32x4_t accd = {0.f, 0.f, 0.f, 0.f};
#pragma unroll
            for (int k = 0; k < 29; ++k) {
                bf16x8_t aa = *(const bf16x8_t*)(as + k * 32);
                bf16x8_t bb = *(const bf16x8_t*)(bp + k * 32);
                accd = __builtin_amdgcn_mfma_f32_16x16x32_bf16(aa, bb, accd, 0, 0, 0);
            }
            int c = wave * 16 + l15;
            if (c < N_HIDDEN) {                        // wave 6 covers cols 96..99
#pragma unroll
                for (int rr = 0; rr < 4; ++rr)
                    out[(size_t)(m0 + quad * 4 + rr) * N_HIDDEN + c] = accd[rr];
            }
        }
        __syncthreads();                               // St reused by next tile
    }
}

// ================= fallback path (if cooperative launch is rejected) =========
__global__ __launch_bounds__(256) void setup_hist(const float* __restrict__ W,
                                                  const float* __restrict__ b,
                                                  const int* __restrict__ a2p,
                                                  __hip_bfloat16* __restrict__ wtb2,
                                                  int* __restrict__ deg,
                                                  unsigned* __restrict__ bucket) {
    int bid = blockIdx.x;
    if (bid < SETUP_BLOCKS) {
        int id = bid * 256 + threadIdx.x;
        int i = id >> 10;
        int k = id & 1023;
        float v = 0.f;
        if (i < N_HIDDEN) {
            if (k < 800) {
                int f = k / N_HIDDEN;
                int j = k - f * N_HIDDEN;
                v = W[f * (N_HIDDEN * N_HIDDEN) + i * N_HIDDEN + j];
            } else if (k < 900) {
                v = b[i * N_HIDDEN + (k - 800)];
            }
        }
        wtb2[id] = __float2bfloat16(v);
    } else {
        int e = (bid - SETUP_BLOCKS) * 256 + threadIdx.x;
        int dest = a2p[e * 2];
        int src  = a2p[e * 2 + 1];
        int slot = atomicAdd(&deg[dest], 1);
        if (slot < MAX_DEG)
            bucket[dest * MAX_DEG + slot] = ((unsigned)e << 14) | (unsigned)src;
    }
}

__global__ __launch_bounds__(512) void fused_edge_gemm(const float* __restrict__ af,
                                                       const float* __restrict__ pf,
                                                       const int* __restrict__ deg,
                                                       const unsigned* __restrict__ bucket,
                                                       const __hip_bfloat16* __restrict__ wtb2,
                                                       float* __restrict__ out) {
    __shared__ __hip_bfloat16 St[16 * SKL];
    int blk  = blockIdx.x;
    int wave = threadIdx.x >> 6;
    int lane = threadIdx.x & 63;
    bool act = (lane < 50);

#pragma unroll
    for (int j = 0; j < 2; ++j) {
        int r = wave * 2 + j;
        int d = __builtin_amdgcn_readfirstlane(blk * 16 + r);
        int n = deg[d];
        if (n > MAX_DEG) n = MAX_DEG;
        const unsigned* sb = bucket + (size_t)d * MAX_DEG;
        float acc[9][2] = {};
        for (int t0 = 0; t0 < n; t0 += 4) {
            float2 a[4];
            unsigned pk[4];
#pragma unroll
            for (int u = 0; u < 4; ++u) {
                int t = t0 + u;
                pk[u] = sb[t < n ? t : 0];
                int src = (int)(pk[u] & 16383u);
                if (t < n && act)
                    a[u] = *(const float2*)(af + src * N_HIDDEN + 2 * lane);
                else
                    a[u] = make_float2(0.f, 0.f);
            }
#pragma unroll
            for (int u = 0; u < 4; ++u) {
                int e = (int)(pk[u] >> 14);
                const float* pe = pf + e * N_FEAT;
#pragma unroll
                for (int f = 0; f < N_FEAT; ++f) {
                    float p = pe[f];
                    acc[f][0] += p * a[u].x;
                    acc[f][1] += p * a[u].y;
                }
                acc[8][0] += a[u].x;
                acc[8][1] += a[u].y;
            }
        }
        __hip_bfloat16* srow = St + r * SKL;
        if (act) {
#pragma unroll
            for (int f = 0; f < 9; ++f) {
                __hip_bfloat162 h;
                h.x = __float2bfloat16(acc[f][0]);
                h.y = __float2bfloat16(acc[f][1]);
                *(__hip_bfloat162*)(srow + f * N_HIDDEN + 2 * lane) = h;
            }
        } else {
            __hip_bfloat162 z;
            z.x = __float2bfloat16(0.f);
            z.y = z.x;
            *(__hip_bfloat162*)(srow + 900 + 2 * (lane - 50)) = z;
        }
    }
    __syncthreads();

    if (wave < 7) {
        int quad = lane >> 4;
        int l15  = lane & 15;
        int m0   = blk * 16;
        const __hip_bfloat16* as = St + l15 * SKL + quad * 8;
        const __hip_bfloat16* bp = wtb2 + (size_t)(wave * 16 + l15) * SW + quad * 8;
        f32x4_t accd = {0.f, 0.f, 0.f, 0.f};
#pragma unroll
        for (int k = 0; k < 29; ++k) {
            bf16x8_t aa = *(const bf16x8_t*)(as + k * 32);
            bf16x8_t bb = *(const bf16x8_t*)(bp + k * 32);
            accd = __builtin_amdgcn_mfma_f32_16x16x32_bf16(aa, bb, accd, 0, 0, 0);
        }
        int c = wave * 16 + l15;
        if (c < N_HIDDEN) {
#pragma unroll
            for (int rr = 0; rr < 4; ++rr)
                out[(size_t)(m0 + quad * 4 + rr) * N_HIDDEN + c] = accd[rr];
        }
    }
}

extern "C" void kernel_launch(void* const* d_in, const int* in_sizes, int n_in,
                              void* d_out, int out_size, void* d_ws, size_t ws_size,
                              hipStream_t stream) {
    const float* pf  = (const float*)d_in[0];   // (64000, 8)
    const float* af  = (const float*)d_in[1];   // (16000, 100)
    const int*   a2p = (const int*)d_in[2];     // (64000, 2)
    const float* W   = (const float*)d_in[3];   // (8, 10000)
    const float* b   = (const float*)d_in[4];   // (10000,)
    float* out = (float*)d_out;                 // (16000, 100) fp32

    char* ws = (char*)d_ws;
    __hip_bfloat16* wtb2 = (__hip_bfloat16*)ws;                 // 112*1024*2 = 229,376 B
    int* deg             = (int*)(ws + 229376);                 //    64,000 B
    unsigned* bucket     = (unsigned*)(ws + 229376 + 64000);    // 16000*32*4 = 2,048,000 B

    void* args[] = {(void*)&pf, (void*)&af, (void*)&a2p, (void*)&W, (void*)&b,
                    (void*)&wtb2, (void*)&deg, (void*)&bucket, (void*)&out};
    hipError_t err = hipLaunchCooperativeKernel((const void*)mega, dim3(GRID_B),
                                                dim3(TPB), args, 0, stream);
    if (err != hipSuccess) {
        // fallback: previous verified 3-dispatch pipeline
        hipMemsetAsync(deg, 0, N_ATOMS * sizeof(int), stream);
        setup_hist<<<SETUP_BLOCKS + HIST_BLOCKS, 256, 0, stream>>>(W, b, a2p, wtb2, deg, bucket);
        fused_edge_gemm<<<N_ATOMS / 16, 512, 0, stream>>>(af, pf, deg, bucket, wtb2, out);
    }
}

// Round 3
// 104.309 us; speedup vs baseline: 3.1861x; 3.1861x over previous
//
#include <hip/hip_runtime.h>
#include <hip/hip_bf16.h>

// Problem constants
#define N_PAIRS   64000
#define N_ATOMS   16000
#define N_FEAT    8
#define N_HIDDEN  100
// Aggregate-first, fused, scalar-metadata pipeline, 3 dispatches (was 4):
//   d1 zero_wtb2: deg[i]=0 (plain stores) + wtb2[i][k]=Wbig[k][i] (bf16)
//   d2 hist:      bucket edges by dest, packed (e<<14)|src, atomicAdd slots
//   d3 fused:     per 16-dest tile: wave-uniform edge loop (SGPR metadata),
//                 af float2 gather lanes 0..49, S-tile in LDS (bf16),
//                 out = S_tile @ wtb2^T via 16x16x32 bf16 MFMA.
// Round-2 post-mortem: cooperative mega-kernel spilled (VGPR_Count=24,
// VALUBusy 1.4%) and ran 255us -> reverted to the verified split pipeline.
// Rounds 0-2 evidence: both kernels are individually small; fixed harness
// overhead (~75-85us incl. 256MiB poison fill) dominates. Only remaining
// structural lever: dispatch count. The memset dispatch is folded into the
// wtb2 builder (plain stores, ordered before the histogram's atomics by the
// dispatch boundary) -> 4 dispatches become 3.
#define SW        1024    // wtb2 row stride (stored transposed: wtb2[i][k])
#define SKL       936     // LDS S-tile row stride (bf16)
#define MAX_DEG   32      // bucket stride per dest (P(deg>32|Poisson(4))~1e-18)

#define SETUP_BLOCKS (112 * 1024 / 256)    // 448
#define HIST_BLOCKS  (N_PAIRS / 256)       // 250

typedef __attribute__((ext_vector_type(8))) short bf16x8_t;   // 8 bf16 = 4 VGPRs
typedef __attribute__((ext_vector_type(4))) float f32x4_t;

// ---- d1: build wtb2[i][k] = Wbig[k][i] (bf16, padded) AND zero deg.
//      No atomics on deg here -> safe; next dispatch orders the histogram.
__global__ __launch_bounds__(256) void zero_wtb2(const float* __restrict__ W,
                                                 const float* __restrict__ b,
                                                 __hip_bfloat16* __restrict__ wtb2,
                                                 int* __restrict__ deg) {
    int id = blockIdx.x * 256 + threadIdx.x;   // < 114688
    if (id < N_ATOMS) deg[id] = 0;             // replaces the hipMemsetAsync dispatch
    int i = id >> 10;                          // 0..111 (output col)
    int k = id & 1023;                         // 0..1023 (contraction index)
    float v = 0.f;
    if (i < N_HIDDEN) {
        if (k < 800) {
            int f = k / N_HIDDEN;
            int j = k - f * N_HIDDEN;
            v = W[f * (N_HIDDEN * N_HIDDEN) + i * N_HIDDEN + j];
        } else if (k < 900) {
            v = b[i * N_HIDDEN + (k - 800)];
        }
    }
    wtb2[id] = __float2bfloat16(v);
}

// ---- d2: histogram edges by dest: packed (edge_id<<14)|src.
__global__ __launch_bounds__(256) void hist(const int* __restrict__ a2p,
                                            int* __restrict__ deg,
                                            unsigned* __restrict__ bucket) {
    int e = blockIdx.x * 256 + threadIdx.x;    // < 64000 exactly
    int dest = a2p[e * 2];
    int src  = a2p[e * 2 + 1];
    int slot = atomicAdd(&deg[dest], 1);
    if (slot < MAX_DEG)
        bucket[dest * MAX_DEG + slot] = ((unsigned)e << 14) | (unsigned)src;
}

// ---- d3: fused aggregation + GEMM. One block = 16 dest atoms, 512 threads.
//      Phase 1: wave w owns tile rows 2w, 2w+1 (serial); per dest the edge
//      loop is WAVE-UNIFORM: packed bucket word via scalar load gives src
//      (af gather address) and edge id (pf scalar loads from dense array);
//      af gathered fp32 float2 by lanes 0..49; batch-4 predicated prefetch,
//      single wait, FMA block with SGPR pf operands. No shfl anywhere.
//      Phase 2: waves 0..6 each do one 16-col n-tile of S_tile @ wtb2^T.
__global__ __launch_bounds__(512) void fused_edge_gemm(const float* __restrict__ af,
                                                       const float* __restrict__ pf,
                                                       const int* __restrict__ deg,
                                                       const unsigned* __restrict__ bucket,
                                                       const __hip_bfloat16* __restrict__ wtb2,
                                                       float* __restrict__ out) {
    __shared__ __hip_bfloat16 St[16 * SKL];            // 29,952 B
    int blk  = blockIdx.x;                             // 0..999
    int wave = threadIdx.x >> 6;
    int lane = threadIdx.x & 63;
    bool act = (lane < 50);                            // cols 2*lane, 2*lane+1

#pragma unroll
    for (int j = 0; j < 2; ++j) {
        int r = wave * 2 + j;                          // tile row 0..15
        int d = __builtin_amdgcn_readfirstlane(blk * 16 + r);   // force SGPR
        int n = deg[d];                                // scalar load
        if (n > MAX_DEG) n = MAX_DEG;                  // P(deg>32|Poisson(4))~1e-18

        const unsigned* sb = bucket + (size_t)d * MAX_DEG;       // SGPR base

        float acc[9][2] = {};                          // f=0..7 weighted, f=8 bias
        for (int t0 = 0; t0 < n; t0 += 4) {
            float2 a[4];
            unsigned pk[4];
#pragma unroll
            for (int u = 0; u < 4; ++u) {
                int t = t0 + u;
                pk[u] = sb[t < n ? t : 0];             // scalar load (clamped)
                int src = (int)(pk[u] & 16383u);       // SGPR
                if (t < n && act)
                    a[u] = *(const float2*)(af + src * N_HIDDEN + 2 * lane);
                else
                    a[u] = make_float2(0.f, 0.f);
            }
#pragma unroll
            for (int u = 0; u < 4; ++u) {
                int e = (int)(pk[u] >> 14);            // SGPR edge id
                const float* pe = pf + e * N_FEAT;     // dense, L2-hot
#pragma unroll
                for (int f = 0; f < N_FEAT; ++f) {
                    float p = pe[f];                   // scalar load -> SGPR operand
                    acc[f][0] += p * a[u].x;
                    acc[f][1] += p * a[u].y;
                }
                acc[8][0] += a[u].x;
                acc[8][1] += a[u].y;
            }
        }

        // write S row to LDS (bf16); lanes 50..63 zero the K-pad cols 900..927
        __hip_bfloat16* srow = St + r * SKL;
        if (act) {
#pragma unroll
            for (int f = 0; f < 9; ++f) {
                __hip_bfloat162 h;
                h.x = __float2bfloat16(acc[f][0]);
                h.y = __float2bfloat16(acc[f][1]);
                *(__hip_bfloat162*)(srow + f * N_HIDDEN + 2 * lane) = h;
            }
        } else {
            __hip_bfloat162 z;
            z.x = __float2bfloat16(0.f);
            z.y = z.x;
            *(__hip_bfloat162*)(srow + 900 + 2 * (lane - 50)) = z;   // 900..927
        }
    }
    __syncthreads();

    // ---- phase 2: out[16 rows] = S_tile @ wtb2^T; wave w -> n-tile w (w<7)
    if (wave < 7) {
        int quad = lane >> 4;
        int l15  = lane & 15;
        int m0   = blk * 16;
        const __hip_bfloat16* as = St + l15 * SKL + quad * 8;
        const __hip_bfloat16* bp = wtb2 + (size_t)(wave * 16 + l15) * SW + quad * 8;
        f32x4_t accd = {0.f, 0.f, 0.f, 0.f};
#pragma unroll
        for (int k = 0; k < 29; ++k) {
            bf16x8_t aa = *(const bf16x8_t*)(as + k * 32);
            bf16x8_t bb = *(const bf16x8_t*)(bp + k * 32);
            accd = __builtin_amdgcn_mfma_f32_16x16x32_bf16(aa, bb, accd, 0, 0, 0);
        }
        int c = wave * 16 + l15;
        if (c < N_HIDDEN) {                            // wave 6 covers cols 96..99
#pragma unroll
            for (int rr = 0; rr < 4; ++rr)
                out[(size_t)(m0 + quad * 4 + rr) * N_HIDDEN + c] = accd[rr];
        }
    }
}

extern "C" void kernel_launch(void* const* d_in, const int* in_sizes, int n_in,
                              void* d_out, int out_size, void* d_ws, size_t ws_size,
                              hipStream_t stream) {
    const float* pf  = (const float*)d_in[0];   // (64000, 8)
    const float* af  = (const float*)d_in[1];   // (16000, 100)
    const int*   a2p = (const int*)d_in[2];     // (64000, 2)
    const float* W   = (const float*)d_in[3];   // (8, 10000)
    const float* b   = (const float*)d_in[4];   // (10000,)
    float* out = (float*)d_out;                 // (16000, 100) fp32

    char* ws = (char*)d_ws;
    __hip_bfloat16* wtb2 = (__hip_bfloat16*)ws;                 // 112*1024*2 = 229,376 B
    int* deg             = (int*)(ws + 229376);                 //    64,000 B
    unsigned* bucket     = (unsigned*)(ws + 229376 + 64000);    // 16000*32*4 = 2,048,000 B

    zero_wtb2<<<SETUP_BLOCKS, 256, 0, stream>>>(W, b, wtb2, deg);
    hist<<<HIST_BLOCKS, 256, 0, stream>>>(a2p, deg, bucket);
    fused_edge_gemm<<<N_ATOMS / 16, 512, 0, stream>>>(af, pf, deg, bucket, wtb2, out);
}

// Round 4
// 92.670 us; speedup vs baseline: 3.5862x; 1.1256x over previous
//
#include <hip/hip_runtime.h>
#include <hip/hip_bf16.h>

// Problem constants
#define N_PAIRS   64000
#define N_ATOMS   16000
#define N_FEAT    8
#define N_HIDDEN  100
// Aggregate-first, fused, scalar-metadata pipeline, 3 dispatches:
//   d1 zero_deg:  deg[i]=0 (63 tiny blocks)
//   d2 hist_wtb2: blocks [0,250) bucket edges by dest (packed (e<<14)|src);
//                 blocks [250,698) build wtb2[i][k]=Wbig[k][i] (bf16).
//                 (wtb2 has no ordering dependence on hist -> same dispatch)
//   d3 fused:     M=32 tile (32 dests/block, 500 blocks, 1024 thr):
//                 phase 1: wave w owns rows 2w,2w+1; wave-uniform edge loop,
//                   SGPR metadata, af float2 gather lanes 0..49, S rows in LDS.
//                 phase 2: split-K GEMM: waves 0..6 k in [0,14), waves 8..14
//                   k in [14,29), B-fragment (wtb2) shared across BOTH 16-row
//                   tiles -> per-block B traffic unchanged at M=32 => total B
//                   L2 traffic halves (208MB -> 104MB); group-B partials
//                   reduced via LDS, group-A adds + stores.
// Evidence through round 3: fixed harness overhead ~77us (incl. 41us poison
// fill); controllable kernel+gap budget ~27us; launch-count and staging
// traffic levers exhausted (<=1us each). This round attacks the largest
// modeled in-kernel cost: phase-2 B re-streaming (~6us) + phase-2 critical
// path + phase-1 wave imbalance.
#define SW        1024    // wtb2 row stride (stored transposed: wtb2[i][k])
#define SKL       936     // LDS S-tile row stride (bf16)
#define MAX_DEG   32      // bucket stride per dest (P(deg>32|Poisson(4))~1e-18)

#define ZERO_BLOCKS  ((N_ATOMS + 255) / 256)      // 63
#define HIST_BLOCKS  (N_PAIRS / 256)              // 250
#define WTB2_BLOCKS  (112 * 1024 / 256)           // 448
#define D2_BLOCKS    (HIST_BLOCKS + WTB2_BLOCKS)  // 698

typedef __attribute__((ext_vector_type(8))) short bf16x8_t;   // 8 bf16 = 4 VGPRs
typedef __attribute__((ext_vector_type(4))) float f32x4_t;

// ---- d1: zero deg (replaces memset dispatch; must precede hist's atomics)
__global__ __launch_bounds__(256) void zero_deg(int* __restrict__ deg) {
    int id = blockIdx.x * 256 + threadIdx.x;
    if (id < N_ATOMS) deg[id] = 0;
}

// ---- d2: histogram + wtb2 build in one dispatch (independent block ranges)
__global__ __launch_bounds__(256) void hist_wtb2(const int* __restrict__ a2p,
                                                 const float* __restrict__ W,
                                                 const float* __restrict__ b,
                                                 int* __restrict__ deg,
                                                 unsigned* __restrict__ bucket,
                                                 __hip_bfloat16* __restrict__ wtb2) {
    int bid = blockIdx.x;
    if (bid < HIST_BLOCKS) {
        int e = bid * 256 + threadIdx.x;           // < 64000 exactly
        int2 pr = ((const int2*)a2p)[e];           // {dest, src} one 8B load
        int slot = atomicAdd(&deg[pr.x], 1);
        if (slot < MAX_DEG)
            bucket[pr.x * MAX_DEG + slot] = ((unsigned)e << 14) | (unsigned)pr.y;
    } else {
        int id = (bid - HIST_BLOCKS) * 256 + threadIdx.x;   // < 114688
        int i = id >> 10;                          // 0..111 (output col)
        int k = id & 1023;                         // 0..1023 (contraction index)
        float v = 0.f;
        if (i < N_HIDDEN) {
            if (k < 800) {
                int f = k / N_HIDDEN;
                int j = k - f * N_HIDDEN;
                v = W[f * (N_HIDDEN * N_HIDDEN) + i * N_HIDDEN + j];
            } else if (k < 900) {
                v = b[i * N_HIDDEN + (k - 800)];
            }
        }
        wtb2[id] = __float2bfloat16(v);
    }
}

// ---- d3: fused aggregation + GEMM. One block = 32 dest atoms, 1024 threads
//      (16 waves). Phase 1 identical math to the verified kernel; phase 2 is
//      split-K with B-fragment reuse across the two 16-row tiles.
__global__ __launch_bounds__(1024) void fused_edge_gemm(const float* __restrict__ af,
                                                        const float* __restrict__ pf,
                                                        const int* __restrict__ deg,
                                                        const unsigned* __restrict__ bucket,
                                                        const __hip_bfloat16* __restrict__ wtb2,
                                                        float* __restrict__ out) {
    __shared__ __hip_bfloat16 St[32 * SKL];            // 59,904 B
    __shared__ float Pb[14 * 256];                     // 14,336 B (split-K partials)
    int blk  = blockIdx.x;                             // 0..499
    int wave = threadIdx.x >> 6;                       // 0..15
    int lane = threadIdx.x & 63;
    bool act = (lane < 50);                            // cols 2*lane, 2*lane+1

    // ---- phase 1: wave w -> S rows 2w, 2w+1 (dests blk*32 + r)
#pragma unroll
    for (int j = 0; j < 2; ++j) {
        int r = wave * 2 + j;                          // tile row 0..31
        int d = __builtin_amdgcn_readfirstlane(blk * 32 + r);   // force SGPR
        int n = deg[d];                                // scalar load
        if (n > MAX_DEG) n = MAX_DEG;                  // P(deg>32|Poisson(4))~1e-18

        const unsigned* sb = bucket + (size_t)d * MAX_DEG;       // SGPR base

        float acc[9][2] = {};                          // f=0..7 weighted, f=8 bias
        for (int t0 = 0; t0 < n; t0 += 4) {
            float2 a[4];
            unsigned pk[4];
#pragma unroll
            for (int u = 0; u < 4; ++u) {
                int t = t0 + u;
                pk[u] = sb[t < n ? t : 0];             // scalar load (clamped)
                int src = (int)(pk[u] & 16383u);       // SGPR
                if (t < n && act)
                    a[u] = *(const float2*)(af + src * N_HIDDEN + 2 * lane);
                else
                    a[u] = make_float2(0.f, 0.f);
            }
#pragma unroll
            for (int u = 0; u < 4; ++u) {
                int e = (int)(pk[u] >> 14);            // SGPR edge id
                const float* pe = pf + e * N_FEAT;     // dense, L2-hot
#pragma unroll
                for (int f = 0; f < N_FEAT; ++f) {
                    float p = pe[f];                   // scalar load -> SGPR operand
                    acc[f][0] += p * a[u].x;
                    acc[f][1] += p * a[u].y;
                }
                acc[8][0] += a[u].x;
                acc[8][1] += a[u].y;
            }
        }

        // write S row to LDS (bf16); lanes 50..63 zero the K-pad cols 900..927
        __hip_bfloat16* srow = St + r * SKL;
        if (act) {
#pragma unroll
            for (int f = 0; f < 9; ++f) {
                __hip_bfloat162 h;
                h.x = __float2bfloat16(acc[f][0]);
                h.y = __float2bfloat16(acc[f][1]);
                *(__hip_bfloat162*)(srow + f * N_HIDDEN + 2 * lane) = h;
            }
        } else {
            __hip_bfloat162 z;
            z.x = __float2bfloat16(0.f);
            z.y = z.x;
            *(__hip_bfloat162*)(srow + 900 + 2 * (lane - 50)) = z;   // 900..927
        }
    }
    __syncthreads();

    // ---- phase 2: out[32 rows] = S_tile @ wtb2^T, split-K over 2 wave groups.
    //      n-tile wt = 0..6 (16 cols each); group A (waves 0..6) k in [0,14),
    //      group B (waves 8..14) k in [14,29). bb shared across both 16-row
    //      tiles (B traffic halved vs M=16).
    int quad = lane >> 4;
    int l15  = lane & 15;
    int wt   = (wave < 7) ? wave : ((wave >= 8 && wave < 15) ? wave - 8 : -1);
    f32x4_t acc0 = {0.f, 0.f, 0.f, 0.f};
    f32x4_t acc1 = {0.f, 0.f, 0.f, 0.f};
    if (wt >= 0) {
        int kb = (wave < 7) ? 0 : 14;
        int ke = (wave < 7) ? 14 : 29;
        const __hip_bfloat16* as0 = St + l15 * SKL + quad * 8;
        const __hip_bfloat16* as1 = St + (16 + l15) * SKL + quad * 8;
        const __hip_bfloat16* bp  = wtb2 + (size_t)(wt * 16 + l15) * SW + quad * 8;
        for (int k = kb; k < ke; ++k) {
            bf16x8_t bb = *(const bf16x8_t*)(bp + k * 32);
            bf16x8_t a0 = *(const bf16x8_t*)(as0 + k * 32);
            bf16x8_t a1 = *(const bf16x8_t*)(as1 + k * 32);
            acc0 = __builtin_amdgcn_mfma_f32_16x16x32_bf16(a0, bb, acc0, 0, 0, 0);
            acc1 = __builtin_amdgcn_mfma_f32_16x16x32_bf16(a1, bb, acc1, 0, 0, 0);
        }
        if (wave >= 8) {                               // group B: stash partials
            float* p0 = Pb + (wt * 2 + 0) * 256 + quad * 4 * 16 + l15;
            float* p1 = Pb + (wt * 2 + 1) * 256 + quad * 4 * 16 + l15;
#pragma unroll
            for (int rr = 0; rr < 4; ++rr) {
                p0[rr * 16] = acc0[rr];
                p1[rr * 16] = acc1[rr];
            }
        }
    }
    __syncthreads();

    if (wave < 7) {                                    // group A: reduce + store
        int c = wave * 16 + l15;
        if (c < N_HIDDEN) {                            // wave 6 covers cols 96..99
            const float* p0 = Pb + (wave * 2 + 0) * 256 + quad * 4 * 16 + l15;
            const float* p1 = Pb + (wave * 2 + 1) * 256 + quad * 4 * 16 + l15;
#pragma unroll
            for (int rr = 0; rr < 4; ++rr) {
                out[(size_t)(blk * 32 + quad * 4 + rr) * N_HIDDEN + c] = acc0[rr] + p0[rr * 16];
                out[(size_t)(blk * 32 + 16 + quad * 4 + rr) * N_HIDDEN + c] = acc1[rr] + p1[rr * 16];
            }
        }
    }
}

extern "C" void kernel_launch(void* const* d_in, const int* in_sizes, int n_in,
                              void* d_out, int out_size, void* d_ws, size_t ws_size,
                              hipStream_t stream) {
    const float* pf  = (const float*)d_in[0];   // (64000, 8)
    const float* af  = (const float*)d_in[1];   // (16000, 100)
    const int*   a2p = (const int*)d_in[2];     // (64000, 2)
    const float* W   = (const float*)d_in[3];   // (8, 10000)
    const float* b   = (const float*)d_in[4];   // (10000,)
    float* out = (float*)d_out;                 // (16000, 100) fp32

    char* ws = (char*)d_ws;
    __hip_bfloat16* wtb2 = (__hip_bfloat16*)ws;                 // 112*1024*2 = 229,376 B
    int* deg             = (int*)(ws + 229376);                 //    64,000 B
    unsigned* bucket     = (unsigned*)(ws + 229376 + 64000);    // 16000*32*4 = 2,048,000 B

    zero_deg<<<ZERO_BLOCKS, 256, 0, stream>>>(deg);
    hist_wtb2<<<D2_BLOCKS, 256, 0, stream>>>(a2p, W, b, deg, bucket, wtb2);
    fused_edge_gemm<<<N_ATOMS / 32, 1024, 0, stream>>>(af, pf, deg, bucket, wtb2, out);
}

// Round 5
// 90.835 us; speedup vs baseline: 3.6587x; 1.0202x over previous
//
#include <hip/hip_runtime.h>
#include <hip/hip_bf16.h>

// Problem constants
#define N_PAIRS   64000
#define N_ATOMS   16000
#define N_FEAT    8
#define N_HIDDEN  100
// Aggregate-first, fused, scalar-metadata pipeline, 3 dispatches:
//   d1 zero_deg:  deg[i]=0
//   d2 hist_wtb2: blocks [0,250) bucket edges by dest (packed (e<<14)|src);
//                 blocks [250,698) build wtb2[i][k]=Wbig[k][i] (bf16).
//   d3 fused:     M=64 tile (64 dests/block, 250 blocks, 1024 thr, 1 blk/CU):
//                 phase 1: wave w builds S rows 4w..4w+3 (wave-uniform edge
//                   loop, SGPR metadata, af float2 gather lanes 0..49).
//                 phase 2: split-K GEMM, B-fragment shared across FOUR 16-row
//                   tiles -> per-block B traffic flat => total B L2 traffic
//                   halves again (93MB -> 46MB). Split-K partials aliased
//                   into St after a barrier (St dead post-MFMA) -> LDS stays
//                   119,808 B.
// Evidence: round-4 (M=16->32 + split-K) was -11.6us; d3 is 1 block/CU at
// 1024 thr (~100 VGPR, 74KB LDS) so M=64 costs no occupancy. Round-2 mega
// failure root-caused to __launch_bounds__(,4) VGPR cap -> spill; no min-
// waves bound used anywhere now.
#define SW        1024    // wtb2 row stride (stored transposed: wtb2[i][k])
#define SKL       936     // LDS S-tile row stride (bf16)
#define MAX_DEG   32      // bucket stride per dest (P(deg>32|Poisson(4))~1e-18)

#define ZERO_BLOCKS  ((N_ATOMS + 255) / 256)      // 63
#define HIST_BLOCKS  (N_PAIRS / 256)              // 250
#define WTB2_BLOCKS  (112 * 1024 / 256)           // 448
#define D2_BLOCKS    (HIST_BLOCKS + WTB2_BLOCKS)  // 698

typedef __attribute__((ext_vector_type(8))) short bf16x8_t;   // 8 bf16 = 4 VGPRs
typedef __attribute__((ext_vector_type(4))) float f32x4_t;

// ---- d1: zero deg (must precede hist's atomics)
__global__ __launch_bounds__(256) void zero_deg(int* __restrict__ deg) {
    int id = blockIdx.x * 256 + threadIdx.x;
    if (id < N_ATOMS) deg[id] = 0;
}

// ---- d2: histogram + wtb2 build in one dispatch (independent block ranges)
__global__ __launch_bounds__(256) void hist_wtb2(const int* __restrict__ a2p,
                                                 const float* __restrict__ W,
                                                 const float* __restrict__ b,
                                                 int* __restrict__ deg,
                                                 unsigned* __restrict__ bucket,
                                                 __hip_bfloat16* __restrict__ wtb2) {
    int bid = blockIdx.x;
    if (bid < HIST_BLOCKS) {
        int e = bid * 256 + threadIdx.x;           // < 64000 exactly
        int2 pr = ((const int2*)a2p)[e];           // {dest, src} one 8B load
        int slot = atomicAdd(&deg[pr.x], 1);
        if (slot < MAX_DEG)
            bucket[pr.x * MAX_DEG + slot] = ((unsigned)e << 14) | (unsigned)pr.y;
    } else {
        int id = (bid - HIST_BLOCKS) * 256 + threadIdx.x;   // < 114688
        int i = id >> 10;                          // 0..111 (output col)
        int k = id & 1023;                         // 0..1023 (contraction index)
        float v = 0.f;
        if (i < N_HIDDEN) {
            if (k < 800) {
                int f = k / N_HIDDEN;
                int j = k - f * N_HIDDEN;
                v = W[f * (N_HIDDEN * N_HIDDEN) + i * N_HIDDEN + j];
            } else if (k < 900) {
                v = b[i * N_HIDDEN + (k - 800)];
            }
        }
        wtb2[id] = __float2bfloat16(v);
    }
}

// ---- d3: fused aggregation + GEMM. One block = 64 dest atoms, 1024 threads
//      (16 waves, 1 block/CU). Phase-1 math identical to the verified kernel.
__global__ __launch_bounds__(1024) void fused_edge_gemm(const float* __restrict__ af,
                                                        const float* __restrict__ pf,
                                                        const int* __restrict__ deg,
                                                        const unsigned* __restrict__ bucket,
                                                        const __hip_bfloat16* __restrict__ wtb2,
                                                        float* __restrict__ out) {
    __shared__ __hip_bfloat16 St[64 * SKL];            // 119,808 B (1 block/CU)
    int blk  = blockIdx.x;                             // 0..249
    int wave = threadIdx.x >> 6;                       // 0..15
    int lane = threadIdx.x & 63;
    bool act = (lane < 50);                            // cols 2*lane, 2*lane+1

    // ---- phase 1: wave w -> S rows 4w..4w+3 (dests blk*64 + r)
    for (int j = 0; j < 4; ++j) {
        int r = wave * 4 + j;                          // tile row 0..63
        int d = __builtin_amdgcn_readfirstlane(blk * 64 + r);   // force SGPR
        int n = deg[d];                                // scalar load
        if (n > MAX_DEG) n = MAX_DEG;                  // P(deg>32|Poisson(4))~1e-18

        const unsigned* sb = bucket + (size_t)d * MAX_DEG;       // SGPR base

        float acc[9][2] = {};                          // f=0..7 weighted, f=8 bias
        for (int t0 = 0; t0 < n; t0 += 4) {
            float2 a[4];
            unsigned pk[4];
#pragma unroll
            for (int u = 0; u < 4; ++u) {
                int t = t0 + u;
                pk[u] = sb[t < n ? t : 0];             // scalar load (clamped)
                int src = (int)(pk[u] & 16383u);       // SGPR
                if (t < n && act)
                    a[u] = *(const float2*)(af + src * N_HIDDEN + 2 * lane);
                else
                    a[u] = make_float2(0.f, 0.f);
            }
#pragma unroll
            for (int u = 0; u < 4; ++u) {
                int e = (int)(pk[u] >> 14);            // SGPR edge id
                const float* pe = pf + e * N_FEAT;     // dense, L2-hot
#pragma unroll
                for (int f = 0; f < N_FEAT; ++f) {
                    float p = pe[f];                   // scalar load -> SGPR operand
                    acc[f][0] += p * a[u].x;
                    acc[f][1] += p * a[u].y;
                }
                acc[8][0] += a[u].x;
                acc[8][1] += a[u].y;
            }
        }

        // write S row to LDS (bf16); lanes 50..63 zero the K-pad cols 900..927
        __hip_bfloat16* srow = St + r * SKL;
        if (act) {
#pragma unroll
            for (int f = 0; f < 9; ++f) {
                __hip_bfloat162 h;
                h.x = __float2bfloat16(acc[f][0]);
                h.y = __float2bfloat16(acc[f][1]);
                *(__hip_bfloat162*)(srow + f * N_HIDDEN + 2 * lane) = h;
            }
        } else {
            __hip_bfloat162 z;
            z.x = __float2bfloat16(0.f);
            z.y = z.x;
            *(__hip_bfloat162*)(srow + 900 + 2 * (lane - 50)) = z;   // 900..927
        }
    }
    __syncthreads();

    // ---- phase 2: out[64 rows] = S_tile @ wtb2^T, split-K over 2 wave groups,
    //      B-fragment reused across 4 row-tiles. n-tile wt = 0..6 (16 cols).
    int quad = lane >> 4;
    int l15  = lane & 15;
    int wt   = (wave < 7) ? wave : ((wave >= 8 && wave < 15) ? wave - 8 : -1);
    f32x4_t acc0 = {0.f, 0.f, 0.f, 0.f};
    f32x4_t acc1 = {0.f, 0.f, 0.f, 0.f};
    f32x4_t acc2 = {0.f, 0.f, 0.f, 0.f};
    f32x4_t acc3 = {0.f, 0.f, 0.f, 0.f};
    if (wt >= 0) {
        int kb = (wave < 7) ? 0 : 14;
        int ke = (wave < 7) ? 14 : 29;
        const __hip_bfloat16* as0 = St + (l15 +  0) * SKL + quad * 8;
        const __hip_bfloat16* as1 = St + (l15 + 16) * SKL + quad * 8;
        const __hip_bfloat16* as2 = St + (l15 + 32) * SKL + quad * 8;
        const __hip_bfloat16* as3 = St + (l15 + 48) * SKL + quad * 8;
        const __hip_bfloat16* bp  = wtb2 + (size_t)(wt * 16 + l15) * SW + quad * 8;
        for (int k = kb; k < ke; ++k) {
            bf16x8_t bb = *(const bf16x8_t*)(bp + k * 32);
            bf16x8_t a0 = *(const bf16x8_t*)(as0 + k * 32);
            bf16x8_t a1 = *(const bf16x8_t*)(as1 + k * 32);
            bf16x8_t a2 = *(const bf16x8_t*)(as2 + k * 32);
            bf16x8_t a3 = *(const bf16x8_t*)(as3 + k * 32);
            acc0 = __builtin_amdgcn_mfma_f32_16x16x32_bf16(a0, bb, acc0, 0, 0, 0);
            acc1 = __builtin_amdgcn_mfma_f32_16x16x32_bf16(a1, bb, acc1, 0, 0, 0);
            acc2 = __builtin_amdgcn_mfma_f32_16x16x32_bf16(a2, bb, acc2, 0, 0, 0);
            acc3 = __builtin_amdgcn_mfma_f32_16x16x32_bf16(a3, bb, acc3, 0, 0, 0);
        }
    }
    __syncthreads();                                   // all St reads complete

    // partials region aliases St (St is dead now); 7*4*256 floats = 28,672 B
    float* Pb = (float*)St;
    if (wave >= 8 && wave < 15) {                      // group B: stash partials
        float* pb = Pb + (size_t)(wave - 8) * 4 * 256 + quad * 64 + l15;
#pragma unroll
        for (int rr = 0; rr < 4; ++rr) {
            pb[0 * 256 + rr * 16] = acc0[rr];
            pb[1 * 256 + rr * 16] = acc1[rr];
            pb[2 * 256 + rr * 16] = acc2[rr];
            pb[3 * 256 + rr * 16] = acc3[rr];
        }
    }
    __syncthreads();

    if (wave < 7) {                                    // group A: reduce + store
        int c = wave * 16 + l15;
        if (c < N_HIDDEN) {                            // wave 6 covers cols 96..99
            const float* pb = Pb + (size_t)wave * 4 * 256 + quad * 64 + l15;
            size_t rowbase = (size_t)blk * 64 + quad * 4;
#pragma unroll
            for (int rr = 0; rr < 4; ++rr) {
                out[(rowbase +  0 + rr) * N_HIDDEN + c] = acc0[rr] + pb[0 * 256 + rr * 16];
                out[(rowbase + 16 + rr) * N_HIDDEN + c] = acc1[rr] + pb[1 * 256 + rr * 16];
                out[(rowbase + 32 + rr) * N_HIDDEN + c] = acc2[rr] + pb[2 * 256 + rr * 16];
                out[(rowbase + 48 + rr) * N_HIDDEN + c] = acc3[rr] + pb[3 * 256 + rr * 16];
            }
        }
    }
}

extern "C" void kernel_launch(void* const* d_in, const int* in_sizes, int n_in,
                              void* d_out, int out_size, void* d_ws, size_t ws_size,
                              hipStream_t stream) {
    const float* pf  = (const float*)d_in[0];   // (64000, 8)
    const float* af  = (const float*)d_in[1];   // (16000, 100)
    const int*   a2p = (const int*)d_in[2];     // (64000, 2)
    const float* W   = (const float*)d_in[3];   // (8, 10000)
    const float* b   = (const float*)d_in[4];   // (10000,)
    float* out = (float*)d_out;                 // (16000, 100) fp32

    char* ws = (char*)d_ws;
    __hip_bfloat16* wtb2 = (__hip_bfloat16*)ws;                 // 112*1024*2 = 229,376 B
    int* deg             = (int*)(ws + 229376);                 //    64,000 B
    unsigned* bucket     = (unsigned*)(ws + 229376 + 64000);    // 16000*32*4 = 2,048,000 B

    zero_deg<<<ZERO_BLOCKS, 256, 0, stream>>>(deg);
    hist_wtb2<<<D2_BLOCKS, 256, 0, stream>>>(a2p, W, b, deg, bucket, wtb2);
    fused_edge_gemm<<<N_ATOMS / 64, 1024, 0, stream>>>(af, pf, deg, bucket, wtb2, out);
}